// Round 7
// baseline (443.808 us; speedup 1.0000x reference)
//
#include <hip/hip_runtime.h>
#include <hip/hip_bf16.h>
#include <stdint.h>

#define BQ   8
#define SEQ  2048
#define EMB  512
#define KVB  32
#define HALF 1024   // keys per split-KV block
#define QTILE 128

typedef __attribute__((ext_vector_type(8))) short short8;
typedef __attribute__((ext_vector_type(4))) float floatx4;
typedef __attribute__((ext_vector_type(4))) unsigned short ushort4_t;
typedef __hip_bfloat16 bf16;

__device__ __forceinline__ unsigned short f2bf(float f) {
    union { bf16 h; unsigned short u; } c;
    c.h = __float2bfloat16(f);
    return c.u;
}

// ---------------- fp32 -> bf16 convert (optionally scaled) ----------------
__global__ __launch_bounds__(256) void cvt_f32_to_bf16(
    const float* __restrict__ in, bf16* __restrict__ out, long n4, float scale)
{
    long i = (long)blockIdx.x * 256 + threadIdx.x;
    if (i >= n4) return;
    floatx4 v = *(const floatx4*)(in + i * 4);
    ushort4_t o;
    o.x = f2bf(v.x * scale);
    o.y = f2bf(v.y * scale);
    o.z = f2bf(v.z * scale);
    o.w = f2bf(v.w * scale);
    *(ushort4_t*)((unsigned short*)out + i * 4) = o;
}

// ---------------- mask(bool, stored as int32 OR uint8) -> f32 bias --------
__global__ __launch_bounds__(256) void mask_to_bias(
    const void* __restrict__ mraw, float* __restrict__ bias)
{
    __shared__ int bad;
    int tid = threadIdx.x;
    if (tid == 0) bad = 0;
    __syncthreads();
    const int* mi = (const int*)mraw;
    int local = 0;
    for (int i = tid; i < 4096; i += 256) {
        unsigned v = (unsigned)mi[i];
        if (v > 1u) local = 1;
    }
    if (local) atomicOr(&bad, 1);
    __syncthreads();
    bool as_int = (bad == 0);
    const unsigned char* mb = (const unsigned char*)mraw;
    for (int i = tid; i < BQ * SEQ; i += 256) {
        int mv = as_int ? mi[i] : (int)mb[i];
        bias[i] = mv ? -1e9f : 0.0f;
    }
}

// ---------------- fused QKV projection ------------------------------------
// grid (12,128): which = bx>>2 selects {Q,K,V}; bcol = (bx&3)*128.
// C[m][n] = sum_k X[m][k] * W[n][k]; V output transposed+key-permuted.
__global__ __launch_bounds__(256) void gemm_qkv(
    const bf16* __restrict__ X,
    const bf16* __restrict__ Wqb, const bf16* __restrict__ Wkb,
    const bf16* __restrict__ Wvb,
    bf16* __restrict__ Qd, bf16* __restrict__ Kd, bf16* __restrict__ Vtp)
{
    __shared__ __attribute__((aligned(16))) bf16 lA[128 * 32];
    __shared__ __attribute__((aligned(16))) bf16 lB[128 * 32];

    const int which = blockIdx.x >> 2;
    const bf16* Bt = (which == 0) ? Wqb : (which == 1) ? Wkb : Wvb;

    const int tid  = threadIdx.x;
    const int lane = tid & 63;
    const int wv   = tid >> 6;
    const int wr   = wv >> 1, wc = wv & 1;
    const long brow = (long)blockIdx.y * 128;
    const long bcol = (long)(blockIdx.x & 3) * 128;

    floatx4 acc[4][4];
#pragma unroll
    for (int m = 0; m < 4; m++)
#pragma unroll
        for (int n = 0; n < 4; n++) acc[m][n] = (floatx4)0.0f;

    const int hi  = lane >> 4;
    const int r16 = lane & 15;

    for (int kt = 0; kt < EMB; kt += 32) {
#pragma unroll
        for (int it = 0; it < 2; ++it) {
            int c = it * 256 + tid;
            const bf16* src = X + (brow + (c >> 2)) * (long)EMB + kt + (c & 3) * 8;
            __builtin_amdgcn_global_load_lds(
                (const __attribute__((address_space(1))) void*)src,
                (__attribute__((address_space(3))) void*)(&lA[(it * 256 + wv * 64) * 8]),
                16, 0, 0);
        }
#pragma unroll
        for (int it = 0; it < 2; ++it) {
            int c = it * 256 + tid;
            const bf16* src = Bt + (bcol + (c >> 2)) * (long)EMB + kt + (c & 3) * 8;
            __builtin_amdgcn_global_load_lds(
                (const __attribute__((address_space(1))) void*)src,
                (__attribute__((address_space(3))) void*)(&lB[(it * 256 + wv * 64) * 8]),
                16, 0, 0);
        }
        __syncthreads();

        short8 af[4], bfr[4];
#pragma unroll
        for (int m = 0; m < 4; m++)
            af[m] = *(const short8*)&lA[(wr * 64 + m * 16 + r16) * 32 + hi * 8];
#pragma unroll
        for (int n = 0; n < 4; n++)
            bfr[n] = *(const short8*)&lB[(wc * 64 + n * 16 + r16) * 32 + hi * 8];
#pragma unroll
        for (int m = 0; m < 4; m++)
#pragma unroll
            for (int n = 0; n < 4; n++)
                acc[m][n] = __builtin_amdgcn_mfma_f32_16x16x32_bf16(
                    af[m], bfr[n], acc[m][n], 0, 0, 0);
        __syncthreads();
    }

#pragma unroll
    for (int m = 0; m < 4; m++) {
#pragma unroll
        for (int n = 0; n < 4; n++) {
#pragma unroll
            for (int j = 0; j < 4; j++) {
                long row = brow + wr * 64 + m * 16 + hi * 4 + j;
                long col = bcol + wc * 64 + n * 16 + r16;
                float v = acc[m][n][j];
                if (which == 0) {
                    Qd[row * EMB + col] = __float2bfloat16(v);
                } else if (which == 1) {
                    Kd[row * EMB + col] = __float2bfloat16(v);
                } else {
                    // Vtp[b][e][key], keys permuted within each 32-block:
                    // pos = ((k>>2)&3)*8 + ((k>>4)&1)*4 + (k&3)
                    long bb = row >> 11;
                    int  t  = (int)(row & 2047);
                    int  t5 = t & 31;
                    int  tp = (t & ~31) | (((t5 >> 2) & 3) << 3)
                            | (((t5 >> 4) & 1) << 2) | (t5 & 3);
                    Vtp[(bb * EMB + col) * SEQ + tp] = __float2bfloat16(v);
                }
            }
        }
    }
}

// ---------------- fused flash attention: 8 waves, swapped-S ---------------
// grid 256: bid&7=batch (XCD), (bid>>3)&15=qtile(128 rows), bid>>7=KV half.
// Wave w owns q-rows q0+w*16..+15 (all 512 e-cols). S^T = mfma(K,Q):
// lane(hi,r16) holds P[q=w*16+r16][keys {4hi+j, 16+4hi+j}] -> in-register
// softmax. PV: pa=[p0,p1] bf16; B-frag = ONE global dwordx4 from permuted
// Vtp (no LDS, no repack; L1/L2-served, parallel with K's LDS pipe).
// K double-buffered in LDS (XOR swizzle); 1 barrier/tile.
__global__ __launch_bounds__(512) void flash_attn(
    const bf16* __restrict__ Q, const bf16* __restrict__ K,
    const bf16* __restrict__ Vtp, const float* __restrict__ bias,
    float* __restrict__ part, float2* __restrict__ ml)
{
    __shared__ __attribute__((aligned(16))) bf16 Klds[2][KVB * EMB];  // 64KB
    __shared__ float biasLds[HALF];                                    // 4KB

    const int tid  = threadIdx.x;
    const int lane = tid & 63;
    const int wv   = tid >> 6;          // 0..7
    const int r16  = lane & 15, hi = lane >> 4;

    const int bid = blockIdx.x;
    const int b   = bid & 7;            // batch -> XCD
    const int qt  = (bid >> 3) & 15;    // 0..15
    const int h   = bid >> 7;           // KV half
    const long q0  = (long)qt * QTILE;
    const long kv0 = (long)h * HALF;
    const int NT   = HALF / KVB;        // 32

    const bf16* Qb = Q   + (long)b * SEQ * EMB;
    const bf16* Kb = K   + (long)b * SEQ * EMB + kv0 * EMB;
    const bf16* Vb = Vtp + (long)b * EMB * SEQ;
    const float* biasb = bias + (long)b * SEQ + kv0;

    if (tid < HALF / 4)
        *(floatx4*)&biasLds[tid * 4] = *(const floatx4*)&biasb[tid * 4];

    // front-half Q fragments hoisted (ks 0..7); back half reloaded per tile
    const bf16* qrow = Qb + (q0 + wv * 16 + r16) * EMB;
    short8 qf[8];
#pragma unroll
    for (int ks = 0; ks < 8; ks++)
        qf[ks] = *(const short8*)(qrow + ks * 32 + hi * 8);

    floatx4 oacc[32];
#pragma unroll
    for (int nf = 0; nf < 32; nf++) oacc[nf] = (floatx4)0.f;

    float m_r = -3e38f, l_r = 0.f;

    // stage K tile (32x512, XOR-swizzled 16B chunks)
    auto stageK = [&](int buf, int t) {
        bf16* kd = &Klds[buf][0];
#pragma unroll
        for (int i = 0; i < 4; i++) {
            int c = i * 512 + tid;          // chunk id 0..2047
            int row = c >> 6, cc = c & 63;
            const bf16* src = Kb + ((long)t * KVB + row) * EMB + ((cc ^ (row & 7)) << 3);
            __builtin_amdgcn_global_load_lds(
                (const __attribute__((address_space(1))) void*)src,
                (__attribute__((address_space(3))) void*)(kd + c * 8),
                16, 0, 0);
        }
    };

    stageK(0, 0);
    __syncthreads();

    for (int t = 0; t < NT; t++) {
        const int cur = t & 1;
        if (t + 1 < NT) stageK(cur ^ 1, t + 1);

        // back-half Q frags (L2-resident), issued early
        short8 qh[8];
#pragma unroll
        for (int i = 0; i < 8; i++)
            qh[i] = *(const short8*)(qrow + (8 + i) * 32 + hi * 8);

        // ---- S^T = mfma(A=K, B=Q): c0 keys 0..15, c1 keys 16..31 ----
        floatx4 c0 = (floatx4)0.f, c1 = (floatx4)0.f;
        const char* kbase = (const char*)&Klds[cur][0];
        const int rowb0 = r16 * 1024, rowb1 = rowb0 + 16 * 1024;
        const int sw = r16 & 7;
        __builtin_amdgcn_s_setprio(1);
#pragma unroll
        for (int ks = 0; ks < 8; ks++) {
            const int cc = ((ks * 4 + hi) ^ sw) << 4;
            short8 k0 = *(const short8*)(kbase + rowb0 + cc);
            c0 = __builtin_amdgcn_mfma_f32_16x16x32_bf16(k0, qf[ks], c0, 0, 0, 0);
            short8 k1 = *(const short8*)(kbase + rowb1 + cc);
            c1 = __builtin_amdgcn_mfma_f32_16x16x32_bf16(k1, qf[ks], c1, 0, 0, 0);
        }
#pragma unroll
        for (int ks = 8; ks < 16; ks++) {
            const int cc = ((ks * 4 + hi) ^ sw) << 4;
            short8 k0 = *(const short8*)(kbase + rowb0 + cc);
            c0 = __builtin_amdgcn_mfma_f32_16x16x32_bf16(k0, qh[ks - 8], c0, 0, 0, 0);
            short8 k1 = *(const short8*)(kbase + rowb1 + cc);
            c1 = __builtin_amdgcn_mfma_f32_16x16x32_bf16(k1, qh[ks - 8], c1, 0, 0, 0);
        }
        __builtin_amdgcn_s_setprio(0);

        // ---- in-register online softmax (lane owns q-row r16) ----
        float s0[4], s1[4];
#pragma unroll
        for (int j = 0; j < 4; j++) {
            s0[j] = c0[j] + biasLds[t * KVB + hi * 4 + j];
            s1[j] = c1[j] + biasLds[t * KVB + 16 + hi * 4 + j];
        }
        float tmax = fmaxf(fmaxf(fmaxf(s0[0], s0[1]), fmaxf(s0[2], s0[3])),
                           fmaxf(fmaxf(s1[0], s1[1]), fmaxf(s1[2], s1[3])));
        tmax = fmaxf(tmax, __shfl_xor(tmax, 16));
        tmax = fmaxf(tmax, __shfl_xor(tmax, 32));

        float sc = 1.0f;
        int resc = 0;
        if (tmax > m_r + 8.0f) {                  // defer-max (T13)
            sc = __expf(m_r - tmax);
            m_r = tmax;
            resc = 1;
        }
        float p0[4], p1[4], rsum = 0.f;
#pragma unroll
        for (int j = 0; j < 4; j++) {
            p0[j] = __expf(s0[j] - m_r);
            p1[j] = __expf(s1[j] - m_r);
            rsum += p0[j] + p1[j];
        }
        rsum += __shfl_xor(rsum, 16);
        rsum += __shfl_xor(rsum, 32);
        l_r = l_r * sc + rsum;

        short8 pa;                                 // slots [p0, p1] match Vtp perm
#pragma unroll
        for (int j = 0; j < 4; j++) {
            pa[j]     = (short)f2bf(p0[j]);
            pa[4 + j] = (short)f2bf(p1[j]);
        }

        if (__any(resc)) {                         // rare O-rescale
#pragma unroll
            for (int j = 0; j < 4; j++) {
                float f = __shfl(sc, hi * 4 + j);
#pragma unroll
                for (int nf = 0; nf < 32; nf++) oacc[nf][j] *= f;
            }
        }

        // ---- O += P @ V: B-frag direct from global Vtp, 2-group pipeline --
        const bf16* vpb = Vb + (long)r16 * SEQ + kv0 + (long)t * KVB + hi * 8;
        const long VSTEP = 16 * SEQ;
        short8 va[4], vb2[4];
#pragma unroll
        for (int i = 0; i < 4; i++)
            va[i] = *(const short8*)(vpb + i * VSTEP);
#pragma unroll
        for (int g = 0; g < 8; g += 2) {
            if (g + 1 < 8) {
#pragma unroll
                for (int i = 0; i < 4; i++)
                    vb2[i] = *(const short8*)(vpb + ((g + 1) * 4 + i) * VSTEP);
            }
            __builtin_amdgcn_s_setprio(1);
#pragma unroll
            for (int i = 0; i < 4; i++)
                oacc[g * 4 + i] = __builtin_amdgcn_mfma_f32_16x16x32_bf16(
                    pa, va[i], oacc[g * 4 + i], 0, 0, 0);
            __builtin_amdgcn_s_setprio(0);
            if (g + 2 < 8) {
#pragma unroll
                for (int i = 0; i < 4; i++)
                    va[i] = *(const short8*)(vpb + ((g + 2) * 4 + i) * VSTEP);
            }
            __builtin_amdgcn_s_setprio(1);
#pragma unroll
            for (int i = 0; i < 4; i++)
                oacc[(g + 1) * 4 + i] = __builtin_amdgcn_mfma_f32_16x16x32_bf16(
                    pa, vb2[i], oacc[(g + 1) * 4 + i], 0, 0, 0);
            __builtin_amdgcn_s_setprio(0);
        }

        __syncthreads();   // staged t+1 drained; K buffers swappable
    }

    // ---- epilogue: unnormalized O partial + (m,l) per q-row ----
    float* pb = part + (long)bid * QTILE * EMB;
#pragma unroll
    for (int j = 0; j < 4; j++) {
        long row = wv * 16 + hi * 4 + j;
#pragma unroll
        for (int cf = 0; cf < 32; cf++)
            pb[row * EMB + cf * 16 + r16] = oacc[cf][j];
    }
    if (hi == 0)
        ml[(long)bid * QTILE + wv * 16 + r16] = make_float2(m_r, l_r);
}

// ---------------- combine the two KV halves -------------------------------
__global__ __launch_bounds__(128) void combine_halves(
    const float* __restrict__ part, const float2* __restrict__ ml,
    float* __restrict__ out)
{
    const int r  = blockIdx.x;              // 0..16383 global q-row
    const int b  = r >> 11;
    const int rb = r & 2047;
    const int qt = rb >> 7;
    const int rr = rb & 127;
    const int s0 = qt * 8 + b;              // slot of half 0
    const int s1 = s0 + 128;

    float2 ml0 = ml[(long)s0 * QTILE + rr];
    float2 ml1 = ml[(long)s1 * QTILE + rr];
    float M  = fmaxf(ml0.x, ml1.x);
    float w0 = __expf(ml0.x - M), w1 = __expf(ml1.x - M);
    float inv = 1.0f / (w0 * ml0.y + w1 * ml1.y);
    w0 *= inv; w1 *= inv;

    const floatx4* p0 = (const floatx4*)(part + ((long)s0 * QTILE + rr) * EMB);
    const floatx4* p1 = (const floatx4*)(part + ((long)s1 * QTILE + rr) * EMB);
    floatx4* po = (floatx4*)(out + (long)r * EMB);
    int c = threadIdx.x;                    // 128 threads x floatx4 = 512
    floatx4 v0 = p0[c], v1 = p1[c];
    po[c] = v0 * w0 + v1 * w1;
}

// --------------------------------------------------------------------------
extern "C" void kernel_launch(void* const* d_in, const int* in_sizes, int n_in,
                              void* d_out, int out_size, void* d_ws, size_t ws_size,
                              hipStream_t stream)
{
    const float* feat = (const float*)d_in[0];
    const void*  mask = d_in[1];
    const float* Wq   = (const float*)d_in[2];
    const float* Wk   = (const float*)d_in[3];
    const float* Wv   = (const float*)d_in[4];
    float* out = (float*)d_out;

    const long M  = (long)BQ * SEQ;
    const long NE = M * EMB;
    const long NW = (long)EMB * EMB;

    char* ws = (char*)d_ws;
    size_t off = 0;
    auto carve = [&](size_t bytes) -> void* {
        void* p = ws + off;
        off = (off + bytes + 4095) & ~(size_t)4095;
        return p;
    };
    bf16*   Xb   = (bf16*)carve(NE * 2);
    bf16*   Wqb  = (bf16*)carve(NW * 2);
    bf16*   Wkb  = (bf16*)carve(NW * 2);
    bf16*   Wvb  = (bf16*)carve(NW * 2);
    bf16*   Qb   = (bf16*)carve(NE * 2);
    bf16*   Kb   = (bf16*)carve(NE * 2);
    bf16*   Vtp  = (bf16*)carve(NE * 2);
    float*  bias = (float*)carve(M * 4);
    float*  part = (float*)carve((long)256 * QTILE * EMB * 4);   // 64MB
    float2* ml   = (float2*)carve((long)256 * QTILE * 8);
    (void)ws_size; (void)in_sizes; (void)n_in; (void)out_size;

    const float qscale = 0.04419417382415922f;  // 512^-0.5 folded into Wq

    cvt_f32_to_bf16<<<dim3((NE / 4 + 255) / 256), dim3(256), 0, stream>>>(feat, Xb, NE / 4, 1.0f);
    cvt_f32_to_bf16<<<dim3((NW / 4 + 255) / 256), dim3(256), 0, stream>>>(Wq, Wqb, NW / 4, qscale);
    cvt_f32_to_bf16<<<dim3((NW / 4 + 255) / 256), dim3(256), 0, stream>>>(Wk, Wkb, NW / 4, 1.0f);
    cvt_f32_to_bf16<<<dim3((NW / 4 + 255) / 256), dim3(256), 0, stream>>>(Wv, Wvb, NW / 4, 1.0f);
    mask_to_bias<<<dim3(1), dim3(256), 0, stream>>>(mask, bias);

    gemm_qkv<<<dim3(12, 128), dim3(256), 0, stream>>>(Xb, Wqb, Wkb, Wvb, Qb, Kb, Vtp);

    flash_attn<<<dim3(256), dim3(512), 0, stream>>>(Qb, Kb, Vtp, bias, part, ml);
    combine_halves<<<dim3(BQ * SEQ), dim3(128), 0, stream>>>(part, ml, out);
}

// Round 8
// 277.584 us; speedup vs baseline: 1.5988x; 1.5988x over previous
//
#include <hip/hip_runtime.h>
#include <hip/hip_bf16.h>
#include <stdint.h>

#define BQ   8
#define SEQ  2048
#define EMB  512
#define KVB  32
#define HALF 1024   // keys per split-KV block
#define QTILE 128

typedef __attribute__((ext_vector_type(8))) short short8;
typedef __attribute__((ext_vector_type(4))) float floatx4;
typedef __attribute__((ext_vector_type(4))) unsigned short ushort4_t;
typedef __hip_bfloat16 bf16;

__device__ __forceinline__ unsigned short f2bf(float f) {
    union { bf16 h; unsigned short u; } c;
    c.h = __float2bfloat16(f);
    return c.u;
}

// ---------------- fp32 -> bf16 convert (optionally scaled) ----------------
__global__ __launch_bounds__(256) void cvt_f32_to_bf16(
    const float* __restrict__ in, bf16* __restrict__ out, long n4, float scale)
{
    long i = (long)blockIdx.x * 256 + threadIdx.x;
    if (i >= n4) return;
    floatx4 v = *(const floatx4*)(in + i * 4);
    ushort4_t o;
    o.x = f2bf(v.x * scale);
    o.y = f2bf(v.y * scale);
    o.z = f2bf(v.z * scale);
    o.w = f2bf(v.w * scale);
    *(ushort4_t*)((unsigned short*)out + i * 4) = o;
}

// ---------------- mask(bool, stored as int32 OR uint8) -> f32 bias --------
__global__ __launch_bounds__(256) void mask_to_bias(
    const void* __restrict__ mraw, float* __restrict__ bias)
{
    __shared__ int bad;
    int tid = threadIdx.x;
    if (tid == 0) bad = 0;
    __syncthreads();
    const int* mi = (const int*)mraw;
    int local = 0;
    for (int i = tid; i < 4096; i += 256) {
        unsigned v = (unsigned)mi[i];
        if (v > 1u) local = 1;
    }
    if (local) atomicOr(&bad, 1);
    __syncthreads();
    bool as_int = (bad == 0);
    const unsigned char* mb = (const unsigned char*)mraw;
    for (int i = tid; i < BQ * SEQ; i += 256) {
        int mv = as_int ? mi[i] : (int)mb[i];
        bias[i] = mv ? -1e9f : 0.0f;
    }
}

// ---------------- fused QKV projection ------------------------------------
// grid (12,128): which = bx>>2 selects {Q,K,V}; bcol = (bx&3)*128.
// C[m][n] = sum_k X[m][k] * W[n][k]; V output transposed+key-permuted.
__global__ __launch_bounds__(256) void gemm_qkv(
    const bf16* __restrict__ X,
    const bf16* __restrict__ Wqb, const bf16* __restrict__ Wkb,
    const bf16* __restrict__ Wvb,
    bf16* __restrict__ Qd, bf16* __restrict__ Kd, bf16* __restrict__ Vtp)
{
    __shared__ __attribute__((aligned(16))) bf16 lA[128 * 32];
    __shared__ __attribute__((aligned(16))) bf16 lB[128 * 32];

    const int which = blockIdx.x >> 2;
    const bf16* Bt = (which == 0) ? Wqb : (which == 1) ? Wkb : Wvb;

    const int tid  = threadIdx.x;
    const int lane = tid & 63;
    const int wv   = tid >> 6;
    const int wr   = wv >> 1, wc = wv & 1;
    const long brow = (long)blockIdx.y * 128;
    const long bcol = (long)(blockIdx.x & 3) * 128;

    floatx4 acc[4][4];
#pragma unroll
    for (int m = 0; m < 4; m++)
#pragma unroll
        for (int n = 0; n < 4; n++) acc[m][n] = (floatx4)0.0f;

    const int hi  = lane >> 4;
    const int r16 = lane & 15;

    for (int kt = 0; kt < EMB; kt += 32) {
#pragma unroll
        for (int it = 0; it < 2; ++it) {
            int c = it * 256 + tid;
            const bf16* src = X + (brow + (c >> 2)) * (long)EMB + kt + (c & 3) * 8;
            __builtin_amdgcn_global_load_lds(
                (const __attribute__((address_space(1))) void*)src,
                (__attribute__((address_space(3))) void*)(&lA[(it * 256 + wv * 64) * 8]),
                16, 0, 0);
        }
#pragma unroll
        for (int it = 0; it < 2; ++it) {
            int c = it * 256 + tid;
            const bf16* src = Bt + (bcol + (c >> 2)) * (long)EMB + kt + (c & 3) * 8;
            __builtin_amdgcn_global_load_lds(
                (const __attribute__((address_space(1))) void*)src,
                (__attribute__((address_space(3))) void*)(&lB[(it * 256 + wv * 64) * 8]),
                16, 0, 0);
        }
        __syncthreads();

        short8 af[4], bfr[4];
#pragma unroll
        for (int m = 0; m < 4; m++)
            af[m] = *(const short8*)&lA[(wr * 64 + m * 16 + r16) * 32 + hi * 8];
#pragma unroll
        for (int n = 0; n < 4; n++)
            bfr[n] = *(const short8*)&lB[(wc * 64 + n * 16 + r16) * 32 + hi * 8];
#pragma unroll
        for (int m = 0; m < 4; m++)
#pragma unroll
            for (int n = 0; n < 4; n++)
                acc[m][n] = __builtin_amdgcn_mfma_f32_16x16x32_bf16(
                    af[m], bfr[n], acc[m][n], 0, 0, 0);
        __syncthreads();
    }

#pragma unroll
    for (int m = 0; m < 4; m++) {
#pragma unroll
        for (int n = 0; n < 4; n++) {
#pragma unroll
            for (int j = 0; j < 4; j++) {
                long row = brow + wr * 64 + m * 16 + hi * 4 + j;
                long col = bcol + wc * 64 + n * 16 + r16;
                float v = acc[m][n][j];
                if (which == 0) {
                    Qd[row * EMB + col] = __float2bfloat16(v);
                } else if (which == 1) {
                    Kd[row * EMB + col] = __float2bfloat16(v);
                } else {
                    // Vtp[b][e][key], keys permuted within each 32-block:
                    // pos = ((k>>2)&3)*8 + ((k>>4)&1)*4 + (k&3)
                    long bb = row >> 11;
                    int  t  = (int)(row & 2047);
                    int  t5 = t & 31;
                    int  tp = (t & ~31) | (((t5 >> 2) & 3) << 3)
                            | (((t5 >> 4) & 1) << 2) | (t5 & 3);
                    Vtp[(bb * EMB + col) * SEQ + tp] = __float2bfloat16(v);
                }
            }
        }
    }
}

// ---------------- fused flash attention: 8 waves, swapped-S ---------------
// grid 256: bid&7=batch (XCD), (bid>>3)&15=qtile(128 rows), bid>>7=KV half.
// S-phase: wave wv owns q-rows q0+wv*16..+15; S^T = mfma(K,Q); in-register
// online softmax; pa (pi-key-ordered short8) written to Plds[128][32] as ONE
// b128 (= PV A-fragment layout). Barrier. PV-phase: wave wv owns e-cols
// wv*64..+63 exclusively: V-frags = 4x b128 direct from permuted global Vtp
// (1x traffic, full cache lines), A-frags = b128 from Plds. K dbuf LDS.
__global__ __launch_bounds__(512) void flash_attn(
    const bf16* __restrict__ Q, const bf16* __restrict__ K,
    const bf16* __restrict__ Vtp, const float* __restrict__ bias,
    float* __restrict__ part, float2* __restrict__ ml)
{
    __shared__ __attribute__((aligned(16))) bf16 Klds[2][KVB * EMB];  // 64KB
    __shared__ __attribute__((aligned(16))) bf16 Plds[QTILE * KVB];   // 8KB
    __shared__ float biasLds[HALF];                                    // 4KB

    const int tid  = threadIdx.x;
    const int lane = tid & 63;
    const int wv   = tid >> 6;          // 0..7
    const int r16  = lane & 15, hi = lane >> 4;

    const int bid = blockIdx.x;
    const int b   = bid & 7;            // batch -> XCD
    const int qt  = (bid >> 3) & 15;    // 0..15
    const int h   = bid >> 7;           // KV half
    const long q0  = (long)qt * QTILE;
    const long kv0 = (long)h * HALF;
    const int NT   = HALF / KVB;        // 32

    const bf16* Qb = Q   + (long)b * SEQ * EMB;
    const bf16* Kb = K   + (long)b * SEQ * EMB + kv0 * EMB;
    const bf16* Vb = Vtp + (long)b * EMB * SEQ;
    const float* biasb = bias + (long)b * SEQ + kv0;

    if (tid < HALF / 4)
        *(floatx4*)&biasLds[tid * 4] = *(const floatx4*)&biasb[tid * 4];

    // front-half Q fragments hoisted (ks 0..7); back half reloaded per tile
    const bf16* qrow = Qb + (q0 + wv * 16 + r16) * EMB;
    short8 qf[8];
#pragma unroll
    for (int ks = 0; ks < 8; ks++)
        qf[ks] = *(const short8*)(qrow + ks * 32 + hi * 8);

    floatx4 oacc[8][4];                  // [rowgroup][colfrag of wave's 64 cols]
#pragma unroll
    for (int rg = 0; rg < 8; rg++)
#pragma unroll
        for (int nf = 0; nf < 4; nf++) oacc[rg][nf] = (floatx4)0.f;

    float m_r = -3e38f, l_r = 0.f;

    // stage K tile (32x512, XOR-swizzled 16B chunks)
    auto stageK = [&](int buf, int t) {
        bf16* kd = &Klds[buf][0];
#pragma unroll
        for (int i = 0; i < 4; i++) {
            int c = i * 512 + tid;          // chunk id 0..2047
            int row = c >> 6, cc = c & 63;
            const bf16* src = Kb + ((long)t * KVB + row) * EMB + ((cc ^ (row & 7)) << 3);
            __builtin_amdgcn_global_load_lds(
                (const __attribute__((address_space(1))) void*)src,
                (__attribute__((address_space(3))) void*)(kd + c * 8),
                16, 0, 0);
        }
    };

    stageK(0, 0);
    __syncthreads();

    for (int t = 0; t < NT; t++) {
        const int cur = t & 1;

        // back-half Q frags (L1-resident after first tile)
        short8 qh[8];
#pragma unroll
        for (int i = 0; i < 8; i++)
            qh[i] = *(const short8*)(qrow + (8 + i) * 32 + hi * 8);

        // ---- S^T = mfma(A=K, B=Q): c0 keys 0..15, c1 keys 16..31 ----
        floatx4 c0 = (floatx4)0.f, c1 = (floatx4)0.f;
        const char* kbase = (const char*)&Klds[cur][0];
        const int rowb0 = r16 * 1024, rowb1 = rowb0 + 16 * 1024;
        const int sw = r16 & 7;
        __builtin_amdgcn_s_setprio(1);
#pragma unroll
        for (int ks = 0; ks < 8; ks++) {
            const int cc = ((ks * 4 + hi) ^ sw) << 4;
            short8 k0 = *(const short8*)(kbase + rowb0 + cc);
            c0 = __builtin_amdgcn_mfma_f32_16x16x32_bf16(k0, qf[ks], c0, 0, 0, 0);
            short8 k1 = *(const short8*)(kbase + rowb1 + cc);
            c1 = __builtin_amdgcn_mfma_f32_16x16x32_bf16(k1, qf[ks], c1, 0, 0, 0);
        }
#pragma unroll
        for (int ks = 8; ks < 16; ks++) {
            const int cc = ((ks * 4 + hi) ^ sw) << 4;
            short8 k0 = *(const short8*)(kbase + rowb0 + cc);
            c0 = __builtin_amdgcn_mfma_f32_16x16x32_bf16(k0, qh[ks - 8], c0, 0, 0, 0);
            short8 k1 = *(const short8*)(kbase + rowb1 + cc);
            c1 = __builtin_amdgcn_mfma_f32_16x16x32_bf16(k1, qh[ks - 8], c1, 0, 0, 0);
        }
        __builtin_amdgcn_s_setprio(0);

        // ---- in-register online softmax (lane owns q-row wv*16+r16) ----
        float s0[4], s1[4];
#pragma unroll
        for (int j = 0; j < 4; j++) {
            s0[j] = c0[j] + biasLds[t * KVB + hi * 4 + j];
            s1[j] = c1[j] + biasLds[t * KVB + 16 + hi * 4 + j];
        }
        float tmax = fmaxf(fmaxf(fmaxf(s0[0], s0[1]), fmaxf(s0[2], s0[3])),
                           fmaxf(fmaxf(s1[0], s1[1]), fmaxf(s1[2], s1[3])));
        tmax = fmaxf(tmax, __shfl_xor(tmax, 16));
        tmax = fmaxf(tmax, __shfl_xor(tmax, 32));

        float sc = 1.0f;
        int resc = 0;
        if (tmax > m_r + 8.0f) {                  // defer-max (T13)
            sc = __expf(m_r - tmax);
            m_r = tmax;
            resc = 1;
        }
        float p0[4], p1[4], rsum = 0.f;
#pragma unroll
        for (int j = 0; j < 4; j++) {
            p0[j] = __expf(s0[j] - m_r);
            p1[j] = __expf(s1[j] - m_r);
            rsum += p0[j] + p1[j];
        }
        rsum += __shfl_xor(rsum, 16);
        rsum += __shfl_xor(rsum, 32);
        l_r = l_r * sc + rsum;

        short8 pa;                                 // pi-ordered: [p0, p1]
#pragma unroll
        for (int j = 0; j < 4; j++) {
            pa[j]     = (short)f2bf(p0[j]);
            pa[4 + j] = (short)f2bf(p1[j]);
        }

        // O-rescale: sc belongs to q-row wv*16+r16 (S-ownership), but oacc
        // rows are rg*16+hi*4+j over ALL rowgroups -> fetch via Plds? No:
        // rescale BEFORE PV using per-row factors from the S-owner lanes.
        // Broadcast sc of q-row rg*16+hi*4+j: that lane is in wave rg, not
        // ours -> exchange through LDS alongside P (scaleLds).
        __shared__ float scaleLds[QTILE];
        if (hi == 0) scaleLds[wv * 16 + r16] = sc;

        // P-write: one b128 per lane, A-fragment layout
        *(short8*)((char*)Plds + (wv * 16 + r16) * 64 + hi * 16) = pa;
        int anyresc = __any(resc);
        __syncthreads();                          // P + scales visible

        if (t + 1 < NT) stageK(cur ^ 1, t + 1);   // overlaps PV

        // V-frags: wave-exclusive e-cols wv*64..+63, full cache lines
        const bf16* vpb = Vb + (long)(wv * 64 + r16) * SEQ + kv0 + (long)t * KVB + hi * 8;
        short8 vf[4];
#pragma unroll
        for (int nf = 0; nf < 4; nf++)
            vf[nf] = *(const short8*)(vpb + (long)nf * 16 * SEQ);

        if (anyresc) {                            // rare O-rescale (block-wide)
#pragma unroll
            for (int j = 0; j < 4; j++) {
                // all rowgroups share row index pattern rg*16+hi*4+j
#pragma unroll
                for (int rg = 0; rg < 8; rg++) {
                    float f = scaleLds[rg * 16 + hi * 4 + j];
#pragma unroll
                    for (int nf = 0; nf < 4; nf++) oacc[rg][nf][j] *= f;
                }
            }
        }

        // ---- PV: O += P @ V ----
        __builtin_amdgcn_s_setprio(1);
#pragma unroll
        for (int rg = 0; rg < 8; rg++) {
            short8 paf = *(const short8*)((const char*)Plds + (rg * 16 + r16) * 64 + hi * 16);
#pragma unroll
            for (int nf = 0; nf < 4; nf++)
                oacc[rg][nf] = __builtin_amdgcn_mfma_f32_16x16x32_bf16(
                    paf, vf[nf], oacc[rg][nf], 0, 0, 0);
        }
        __builtin_amdgcn_s_setprio(0);

        __syncthreads();   // Plds reusable; staged K drained
    }

    // ---- epilogue: unnormalized O partial + (m,l) per q-row ----
    float* pb = part + (long)bid * QTILE * EMB;
#pragma unroll
    for (int rg = 0; rg < 8; rg++)
#pragma unroll
        for (int j = 0; j < 4; j++) {
            long row = rg * 16 + hi * 4 + j;
#pragma unroll
            for (int nf = 0; nf < 4; nf++)
                pb[row * EMB + wv * 64 + nf * 16 + r16] = oacc[rg][nf][j];
        }
    if (hi == 0)
        ml[(long)bid * QTILE + wv * 16 + r16] = make_float2(m_r, l_r);
}

// ---------------- combine the two KV halves -------------------------------
__global__ __launch_bounds__(128) void combine_halves(
    const float* __restrict__ part, const float2* __restrict__ ml,
    float* __restrict__ out)
{
    const int r  = blockIdx.x;              // 0..16383 global q-row
    const int b  = r >> 11;
    const int rb = r & 2047;
    const int qt = rb >> 7;
    const int rr = rb & 127;
    const int s0 = qt * 8 + b;              // slot of half 0
    const int s1 = s0 + 128;

    float2 ml0 = ml[(long)s0 * QTILE + rr];
    float2 ml1 = ml[(long)s1 * QTILE + rr];
    float M  = fmaxf(ml0.x, ml1.x);
    float w0 = __expf(ml0.x - M), w1 = __expf(ml1.x - M);
    float inv = 1.0f / (w0 * ml0.y + w1 * ml1.y);
    w0 *= inv; w1 *= inv;

    const floatx4* p0 = (const floatx4*)(part + ((long)s0 * QTILE + rr) * EMB);
    const floatx4* p1 = (const floatx4*)(part + ((long)s1 * QTILE + rr) * EMB);
    floatx4* po = (floatx4*)(out + (long)r * EMB);
    int c = threadIdx.x;                    // 128 threads x floatx4 = 512
    floatx4 v0 = p0[c], v1 = p1[c];
    po[c] = v0 * w0 + v1 * w1;
}

// --------------------------------------------------------------------------
extern "C" void kernel_launch(void* const* d_in, const int* in_sizes, int n_in,
                              void* d_out, int out_size, void* d_ws, size_t ws_size,
                              hipStream_t stream)
{
    const float* feat = (const float*)d_in[0];
    const void*  mask = d_in[1];
    const float* Wq   = (const float*)d_in[2];
    const float* Wk   = (const float*)d_in[3];
    const float* Wv   = (const float*)d_in[4];
    float* out = (float*)d_out;

    const long M  = (long)BQ * SEQ;
    const long NE = M * EMB;
    const long NW = (long)EMB * EMB;

    char* ws = (char*)d_ws;
    size_t off = 0;
    auto carve = [&](size_t bytes) -> void* {
        void* p = ws + off;
        off = (off + bytes + 4095) & ~(size_t)4095;
        return p;
    };
    bf16*   Xb   = (bf16*)carve(NE * 2);
    bf16*   Wqb  = (bf16*)carve(NW * 2);
    bf16*   Wkb  = (bf16*)carve(NW * 2);
    bf16*   Wvb  = (bf16*)carve(NW * 2);
    bf16*   Qb   = (bf16*)carve(NE * 2);
    bf16*   Kb   = (bf16*)carve(NE * 2);
    bf16*   Vtp  = (bf16*)carve(NE * 2);
    float*  bias = (float*)carve(M * 4);
    float*  part = (float*)carve((long)256 * QTILE * EMB * 4);   // 64MB
    float2* ml   = (float2*)carve((long)256 * QTILE * 8);
    (void)ws_size; (void)in_sizes; (void)n_in; (void)out_size;

    const float qscale = 0.04419417382415922f;  // 512^-0.5 folded into Wq

    cvt_f32_to_bf16<<<dim3((NE / 4 + 255) / 256), dim3(256), 0, stream>>>(feat, Xb, NE / 4, 1.0f);
    cvt_f32_to_bf16<<<dim3((NW / 4 + 255) / 256), dim3(256), 0, stream>>>(Wq, Wqb, NW / 4, qscale);
    cvt_f32_to_bf16<<<dim3((NW / 4 + 255) / 256), dim3(256), 0, stream>>>(Wk, Wkb, NW / 4, 1.0f);
    cvt_f32_to_bf16<<<dim3((NW / 4 + 255) / 256), dim3(256), 0, stream>>>(Wv, Wvb, NW / 4, 1.0f);
    mask_to_bias<<<dim3(1), dim3(256), 0, stream>>>(mask, bias);

    gemm_qkv<<<dim3(12, 128), dim3(256), 0, stream>>>(Xb, Wqb, Wkb, Wvb, Qb, Kb, Vtp);

    flash_attn<<<dim3(256), dim3(512), 0, stream>>>(Qb, Kb, Vtp, bias, part, ml);
    combine_halves<<<dim3(BQ * SEQ), dim3(128), 0, stream>>>(part, ml, out);
}

// Round 9
// 204.430 us; speedup vs baseline: 2.1710x; 1.3578x over previous
//
#include <hip/hip_runtime.h>
#include <hip/hip_bf16.h>
#include <stdint.h>

#define BQ   8
#define SEQ  2048
#define EMB  512
#define KVB  32
#define HALF 1024   // keys per split-KV block
#define QTILE 128

typedef __attribute__((ext_vector_type(8))) short short8;
typedef __attribute__((ext_vector_type(4))) float floatx4;
typedef __attribute__((ext_vector_type(4))) unsigned short ushort4_t;
typedef __hip_bfloat16 bf16;

__device__ __forceinline__ unsigned short f2bf(float f) {
    union { bf16 h; unsigned short u; } c;
    c.h = __float2bfloat16(f);
    return c.u;
}
__device__ __forceinline__ float bf2f(unsigned short u) {
    union { unsigned int i; float f; } c;
    c.i = ((unsigned int)u) << 16;
    return c.f;
}

// ---------------- fp32 -> bf16 convert: X (features) ----------------------
__global__ __launch_bounds__(256) void cvt_x(
    const float* __restrict__ in, bf16* __restrict__ out, long n4)
{
    long i = (long)blockIdx.x * 256 + threadIdx.x;
    if (i >= n4) return;
    floatx4 v = *(const floatx4*)(in + i * 4);
    ushort4_t o;
    o.x = f2bf(v.x); o.y = f2bf(v.y); o.z = f2bf(v.z); o.w = f2bf(v.w);
    *(ushort4_t*)((unsigned short*)out + i * 4) = o;
}

// ---------------- fp32 -> bf16 convert: all three W in one dispatch -------
__global__ __launch_bounds__(256) void cvt_w(
    const float* __restrict__ Wq, const float* __restrict__ Wk,
    const float* __restrict__ Wv,
    bf16* __restrict__ oq, bf16* __restrict__ ok, bf16* __restrict__ ov,
    float qscale)
{
    const int y = blockIdx.y;
    const float* in = (y == 0) ? Wq : (y == 1) ? Wk : Wv;
    bf16* out = (y == 0) ? oq : (y == 1) ? ok : ov;
    const float scale = (y == 0) ? qscale : 1.0f;
    long i = (long)blockIdx.x * 256 + threadIdx.x;   // grid.x = NW/4/256
    floatx4 v = *(const floatx4*)(in + i * 4);
    ushort4_t o;
    o.x = f2bf(v.x * scale); o.y = f2bf(v.y * scale);
    o.z = f2bf(v.z * scale); o.w = f2bf(v.w * scale);
    *(ushort4_t*)((unsigned short*)out + i * 4) = o;
}

// ---------------- mask(bool, stored as int32 OR uint8) -> f32 bias --------
// grid 16; each block redundantly detects layout, writes its slice.
__global__ __launch_bounds__(256) void mask_to_bias(
    const void* __restrict__ mraw, float* __restrict__ bias)
{
    __shared__ int bad;
    int tid = threadIdx.x;
    if (tid == 0) bad = 0;
    __syncthreads();
    const int* mi = (const int*)mraw;
    int local = 0;
    for (int i = tid; i < 4096; i += 256) {
        unsigned v = (unsigned)mi[i];
        if (v > 1u) local = 1;
    }
    if (local) atomicOr(&bad, 1);
    __syncthreads();
    bool as_int = (bad == 0);
    const unsigned char* mb = (const unsigned char*)mraw;
    const int start = blockIdx.x * (BQ * SEQ / 16);
    for (int i = start + tid; i < start + BQ * SEQ / 16; i += 256) {
        int mv = as_int ? mi[i] : (int)mb[i];
        bias[i] = mv ? -1e9f : 0.0f;
    }
}

// ---------------- fused QKV projection, BK=64 -----------------------------
// grid (12,128): which = bx>>2 selects {Q,K,V}; bcol = (bx&3)*128.
// C[m][n] = sum_k X[m][k] * W[n][k]; V output transposed+key-permuted.
// BK=64: 8 K-steps, 32 MFMA/wave between barrier pairs. LDS rows are 128B
// -> XOR-swizzle 16B chunks (cc^(row&7)) on stage + read (G4 trap).
__global__ __launch_bounds__(256) void gemm_qkv(
    const bf16* __restrict__ X,
    const bf16* __restrict__ Wqb, const bf16* __restrict__ Wkb,
    const bf16* __restrict__ Wvb,
    bf16* __restrict__ Qd, bf16* __restrict__ Kd, bf16* __restrict__ Vtp)
{
    __shared__ __attribute__((aligned(16))) bf16 lA[128 * 64];   // 16KB
    __shared__ __attribute__((aligned(16))) bf16 lB[128 * 64];   // 16KB

    const int which = blockIdx.x >> 2;
    const bf16* Bt = (which == 0) ? Wqb : (which == 1) ? Wkb : Wvb;

    const int tid  = threadIdx.x;
    const int lane = tid & 63;
    const int wv   = tid >> 6;
    const int wr   = wv >> 1, wc = wv & 1;
    const long brow = (long)blockIdx.y * 128;
    const long bcol = (long)(blockIdx.x & 3) * 128;

    floatx4 acc[4][4];
#pragma unroll
    for (int m = 0; m < 4; m++)
#pragma unroll
        for (int n = 0; n < 4; n++) acc[m][n] = (floatx4)0.0f;

    const int hi  = lane >> 4;
    const int r16 = lane & 15;

    for (int kt = 0; kt < EMB; kt += 64) {
#pragma unroll
        for (int i = 0; i < 4; ++i) {
            int c = i * 256 + tid;           // chunk 0..1023
            int row = c >> 3, cc = c & 7;
            const bf16* src = X + (brow + row) * (long)EMB + kt + ((cc ^ (row & 7)) << 3);
            __builtin_amdgcn_global_load_lds(
                (const __attribute__((address_space(1))) void*)src,
                (__attribute__((address_space(3))) void*)(&lA[c * 8]),
                16, 0, 0);
        }
#pragma unroll
        for (int i = 0; i < 4; ++i) {
            int c = i * 256 + tid;
            int row = c >> 3, cc = c & 7;
            const bf16* src = Bt + (bcol + row) * (long)EMB + kt + ((cc ^ (row & 7)) << 3);
            __builtin_amdgcn_global_load_lds(
                (const __attribute__((address_space(1))) void*)src,
                (__attribute__((address_space(3))) void*)(&lB[c * 8]),
                16, 0, 0);
        }
        __syncthreads();

#pragma unroll
        for (int h = 0; h < 2; h++) {
            short8 af[4], bfr[4];
#pragma unroll
            for (int m = 0; m < 4; m++) {
                int row = wr * 64 + m * 16 + r16;
                af[m] = *(const short8*)((const char*)lA + row * 128
                                         + (((h * 4 + hi) ^ (row & 7)) << 4));
            }
#pragma unroll
            for (int n = 0; n < 4; n++) {
                int row = wc * 64 + n * 16 + r16;
                bfr[n] = *(const short8*)((const char*)lB + row * 128
                                          + (((h * 4 + hi) ^ (row & 7)) << 4));
            }
#pragma unroll
            for (int m = 0; m < 4; m++)
#pragma unroll
                for (int n = 0; n < 4; n++)
                    acc[m][n] = __builtin_amdgcn_mfma_f32_16x16x32_bf16(
                        af[m], bfr[n], acc[m][n], 0, 0, 0);
        }
        __syncthreads();
    }

#pragma unroll
    for (int m = 0; m < 4; m++) {
#pragma unroll
        for (int n = 0; n < 4; n++) {
#pragma unroll
            for (int j = 0; j < 4; j++) {
                long row = brow + wr * 64 + m * 16 + hi * 4 + j;
                long col = bcol + wc * 64 + n * 16 + r16;
                float v = acc[m][n][j];
                if (which == 0) {
                    Qd[row * EMB + col] = __float2bfloat16(v);
                } else if (which == 1) {
                    Kd[row * EMB + col] = __float2bfloat16(v);
                } else {
                    // Vtp[b][e][key], keys permuted within each 32-block:
                    // pos = ((k>>2)&3)*8 + ((k>>4)&1)*4 + (k&3)
                    long bb = row >> 11;
                    int  t  = (int)(row & 2047);
                    int  t5 = t & 31;
                    int  tp = (t & ~31) | (((t5 >> 2) & 3) << 3)
                            | (((t5 >> 4) & 1) << 2) | (t5 & 3);
                    Vtp[(bb * EMB + col) * SEQ + tp] = __float2bfloat16(v);
                }
            }
        }
    }
}

// ---------------- fused flash attention (R6 structure) --------------------
// grid 256: bid&7=batch (XCD), (bid>>3)&15=qtile(128 rows), bid>>7=KV half.
// Wave w owns q-rows q0+w*16..+15 (all 512 e-cols). S^T = mfma(K,Q):
// lane(hi,r16) holds P[q=w*16+r16][keys {4hi+j, 16+4hi+j}] -> in-register
// softmax. PV: pa=[p0,p1] bf16; B-frag = ONE b128 from key-permuted Vlds.
// K,V double-buffered LDS; 1 barrier/tile. V chunk rotation (col>>1)&3
// (2-way banks; the (col&3) variant was 4-way).
__global__ __launch_bounds__(512) void flash_attn(
    const bf16* __restrict__ Q, const bf16* __restrict__ K,
    const bf16* __restrict__ Vtp, const float* __restrict__ bias,
    bf16* __restrict__ part, float2* __restrict__ ml)
{
    __shared__ __attribute__((aligned(16))) char smem[2 * 32768 + 2 * 32768 + HALF * 4];
    bf16* Klds0 = (bf16*)smem;                         // [2][32*512]
    bf16* Vlds0 = (bf16*)(smem + 65536);               // [2][512*32] permuted keys
    float* biasLds = (float*)(smem + 131072);          // [1024]

    const int tid  = threadIdx.x;
    const int lane = tid & 63;
    const int wv   = tid >> 6;          // 0..7
    const int r16  = lane & 15, hi = lane >> 4;

    const int bid = blockIdx.x;
    const int b   = bid & 7;            // batch -> XCD
    const int qt  = (bid >> 3) & 15;    // 0..15
    const int h   = bid >> 7;           // KV half
    const long q0  = (long)qt * QTILE;
    const long kv0 = (long)h * HALF;
    const int NT   = HALF / KVB;        // 32

    const bf16* Qb = Q   + (long)b * SEQ * EMB;
    const bf16* Kb = K   + (long)b * SEQ * EMB + kv0 * EMB;
    const bf16* Vb = Vtp + (long)b * EMB * SEQ;
    const float* biasb = bias + (long)b * SEQ + kv0;

    if (tid < HALF / 4)
        *(floatx4*)&biasLds[tid * 4] = *(const floatx4*)&biasb[tid * 4];

    // front-half Q fragments hoisted (ks 0..7); back half reloaded per tile
    const bf16* qrow = Qb + (q0 + wv * 16 + r16) * EMB;
    short8 qf[8];
#pragma unroll
    for (int ks = 0; ks < 8; ks++)
        qf[ks] = *(const short8*)(qrow + ks * 32 + hi * 8);

    floatx4 oacc[32];
#pragma unroll
    for (int nf = 0; nf < 32; nf++) oacc[nf] = (floatx4)0.f;

    float m_r = -3e38f, l_r = 0.f;

    // stage K tile (32x512, XOR-swz chunks) + V tile (512x32 permuted,
    // 16B-chunk rotation by (col>>1)&3). 8 x global_load_lds per thread.
    auto stage = [&](int buf, int t) {
        bf16* kd = Klds0 + buf * (KVB * EMB);
        bf16* vd = Vlds0 + buf * (EMB * KVB);
#pragma unroll
        for (int i = 0; i < 4; i++) {
            int c = i * 512 + tid;          // K chunk id
            int row = c >> 6, cc = c & 63;
            const bf16* src = Kb + ((long)t * KVB + row) * EMB + ((cc ^ (row & 7)) << 3);
            __builtin_amdgcn_global_load_lds(
                (const __attribute__((address_space(1))) void*)src,
                (__attribute__((address_space(3))) void*)(kd + c * 8),
                16, 0, 0);
        }
#pragma unroll
        for (int i = 0; i < 4; i++) {
            int c = i * 512 + tid;          // V chunk id
            int col = c >> 2, ch = c & 3;
            const bf16* src = Vb + (long)col * SEQ + kv0 + t * KVB
                            + ((ch ^ ((col >> 1) & 3)) << 3);
            __builtin_amdgcn_global_load_lds(
                (const __attribute__((address_space(1))) void*)src,
                (__attribute__((address_space(3))) void*)(vd + c * 8),
                16, 0, 0);
        }
    };

    stage(0, 0);
    __syncthreads();

    for (int t = 0; t < NT; t++) {
        const int cur = t & 1;
        if (t + 1 < NT) stage(cur ^ 1, t + 1);

        // back-half Q frags (L1-resident after first tile), issued early
        short8 qh[8];
#pragma unroll
        for (int i = 0; i < 8; i++)
            qh[i] = *(const short8*)(qrow + (8 + i) * 32 + hi * 8);

        // ---- S^T = mfma(A=K, B=Q): c0 keys 0..15, c1 keys 16..31 ----
        floatx4 c0 = (floatx4)0.f, c1 = (floatx4)0.f;
        const char* kbase = (const char*)(Klds0 + cur * (KVB * EMB));
        const int rowb0 = r16 * 1024, rowb1 = rowb0 + 16 * 1024;
        const int sw = r16 & 7;
        __builtin_amdgcn_s_setprio(1);
#pragma unroll
        for (int ks = 0; ks < 8; ks++) {
            const int cc = ((ks * 4 + hi) ^ sw) << 4;
            short8 k0 = *(const short8*)(kbase + rowb0 + cc);
            c0 = __builtin_amdgcn_mfma_f32_16x16x32_bf16(k0, qf[ks], c0, 0, 0, 0);
            short8 k1 = *(const short8*)(kbase + rowb1 + cc);
            c1 = __builtin_amdgcn_mfma_f32_16x16x32_bf16(k1, qf[ks], c1, 0, 0, 0);
        }
#pragma unroll
        for (int ks = 8; ks < 16; ks++) {
            const int cc = ((ks * 4 + hi) ^ sw) << 4;
            short8 k0 = *(const short8*)(kbase + rowb0 + cc);
            c0 = __builtin_amdgcn_mfma_f32_16x16x32_bf16(k0, qh[ks - 8], c0, 0, 0, 0);
            short8 k1 = *(const short8*)(kbase + rowb1 + cc);
            c1 = __builtin_amdgcn_mfma_f32_16x16x32_bf16(k1, qh[ks - 8], c1, 0, 0, 0);
        }
        __builtin_amdgcn_s_setprio(0);

        // ---- in-register online softmax (lane owns q-row r16) ----
        float s0[4], s1[4];
#pragma unroll
        for (int j = 0; j < 4; j++) {
            s0[j] = c0[j] + biasLds[t * KVB + hi * 4 + j];
            s1[j] = c1[j] + biasLds[t * KVB + 16 + hi * 4 + j];
        }
        float tmax = fmaxf(fmaxf(fmaxf(s0[0], s0[1]), fmaxf(s0[2], s0[3])),
                           fmaxf(fmaxf(s1[0], s1[1]), fmaxf(s1[2], s1[3])));
        tmax = fmaxf(tmax, __shfl_xor(tmax, 16));
        tmax = fmaxf(tmax, __shfl_xor(tmax, 32));

        float sc = 1.0f;
        int resc = 0;
        if (tmax > m_r + 8.0f) {                  // defer-max (T13)
            sc = __expf(m_r - tmax);
            m_r = tmax;
            resc = 1;
        }
        float p0[4], p1[4], rsum = 0.f;
#pragma unroll
        for (int j = 0; j < 4; j++) {
            p0[j] = __expf(s0[j] - m_r);
            p1[j] = __expf(s1[j] - m_r);
            rsum += p0[j] + p1[j];
        }
        rsum += __shfl_xor(rsum, 16);
        rsum += __shfl_xor(rsum, 32);
        l_r = l_r * sc + rsum;

        short8 pa;                                 // slots [p0, p1] match Vtp perm
#pragma unroll
        for (int j = 0; j < 4; j++) {
            pa[j]     = (short)f2bf(p0[j]);
            pa[4 + j] = (short)f2bf(p1[j]);
        }

        if (__any(resc)) {                         // rare O-rescale
#pragma unroll
            for (int j = 0; j < 4; j++) {
                float f = __shfl(sc, hi * 4 + j);
#pragma unroll
                for (int nf = 0; nf < 32; nf++) oacc[nf][j] *= f;
            }
        }

        // ---- O += P @ V: B-frag = one b128 from permuted Vlds ----
        const char* vbase = (const char*)(Vlds0 + cur * (EMB * KVB));
        __builtin_amdgcn_s_setprio(1);
#pragma unroll
        for (int cf = 0; cf < 32; cf++) {
            const int col = cf * 16 + r16;
            short8 vf = *(const short8*)(vbase + col * 64 + ((hi ^ ((col >> 1) & 3)) << 4));
            oacc[cf] = __builtin_amdgcn_mfma_f32_16x16x32_bf16(pa, vf, oacc[cf], 0, 0, 0);
        }
        __builtin_amdgcn_s_setprio(0);

        __syncthreads();   // staged t+1 drained; buffers swappable
    }

    // ---- epilogue: unnormalized bf16 O partial + (m,l) per q-row ----
    bf16* pb = part + (long)bid * QTILE * EMB;
#pragma unroll
    for (int j = 0; j < 4; j++) {
        long row = wv * 16 + hi * 4 + j;
#pragma unroll
        for (int cf = 0; cf < 32; cf++)
            pb[row * EMB + cf * 16 + r16] = __float2bfloat16(oacc[cf][j]);
    }
    if (hi == 0)
        ml[(long)bid * QTILE + wv * 16 + r16] = make_float2(m_r, l_r);
}

// ---------------- combine the two KV halves (bf16 partials) ---------------
__global__ __launch_bounds__(128) void combine_halves(
    const bf16* __restrict__ part, const float2* __restrict__ ml,
    float* __restrict__ out)
{
    const int r  = blockIdx.x;              // 0..16383 global q-row
    const int b  = r >> 11;
    const int rb = r & 2047;
    const int qt = rb >> 7;
    const int rr = rb & 127;
    const int s0 = qt * 8 + b;              // slot of half 0
    const int s1 = s0 + 128;

    float2 ml0 = ml[(long)s0 * QTILE + rr];
    float2 ml1 = ml[(long)s1 * QTILE + rr];
    float M  = fmaxf(ml0.x, ml1.x);
    float w0 = __expf(ml0.x - M), w1 = __expf(ml1.x - M);
    float inv = 1.0f / (w0 * ml0.y + w1 * ml1.y);
    w0 *= inv; w1 *= inv;

    const ushort4_t* p0 = (const ushort4_t*)((const unsigned short*)part
                          + ((long)s0 * QTILE + rr) * EMB);
    const ushort4_t* p1 = (const ushort4_t*)((const unsigned short*)part
                          + ((long)s1 * QTILE + rr) * EMB);
    floatx4* po = (floatx4*)(out + (long)r * EMB);
    int c = threadIdx.x;                    // 128 threads x 4 = 512
    ushort4_t a = p0[c], d = p1[c];
    floatx4 o;
    o.x = bf2f(a.x) * w0 + bf2f(d.x) * w1;
    o.y = bf2f(a.y) * w0 + bf2f(d.y) * w1;
    o.z = bf2f(a.z) * w0 + bf2f(d.z) * w1;
    o.w = bf2f(a.w) * w0 + bf2f(d.w) * w1;
    po[c] = o;
}

// --------------------------------------------------------------------------
extern "C" void kernel_launch(void* const* d_in, const int* in_sizes, int n_in,
                              void* d_out, int out_size, void* d_ws, size_t ws_size,
                              hipStream_t stream)
{
    const float* feat = (const float*)d_in[0];
    const void*  mask = d_in[1];
    const float* Wq   = (const float*)d_in[2];
    const float* Wk   = (const float*)d_in[3];
    const float* Wv   = (const float*)d_in[4];
    float* out = (float*)d_out;

    const long M  = (long)BQ * SEQ;
    const long NE = M * EMB;
    const long NW = (long)EMB * EMB;

    char* ws = (char*)d_ws;
    size_t off = 0;
    auto carve = [&](size_t bytes) -> void* {
        void* p = ws + off;
        off = (off + bytes + 4095) & ~(size_t)4095;
        return p;
    };
    bf16*   Xb   = (bf16*)carve(NE * 2);
    bf16*   Wqb  = (bf16*)carve(NW * 2);
    bf16*   Wkb  = (bf16*)carve(NW * 2);
    bf16*   Wvb  = (bf16*)carve(NW * 2);
    bf16*   Qb   = (bf16*)carve(NE * 2);
    bf16*   Kb   = (bf16*)carve(NE * 2);
    bf16*   Vtp  = (bf16*)carve(NE * 2);
    float*  bias = (float*)carve(M * 4);
    bf16*   part = (bf16*)carve((long)256 * QTILE * EMB * 2);   // 32MB
    float2* ml   = (float2*)carve((long)256 * QTILE * 8);
    (void)ws_size; (void)in_sizes; (void)n_in; (void)out_size;

    const float qscale = 0.04419417382415922f;  // 512^-0.5 folded into Wq

    cvt_x<<<dim3((NE / 4 + 255) / 256), dim3(256), 0, stream>>>(feat, Xb, NE / 4);
    cvt_w<<<dim3(NW / 4 / 256, 3), dim3(256), 0, stream>>>(
        Wq, Wk, Wv, Wqb, Wkb, Wvb, qscale);
    mask_to_bias<<<dim3(16), dim3(256), 0, stream>>>(mask, bias);

    gemm_qkv<<<dim3(12, 128), dim3(256), 0, stream>>>(Xb, Wqb, Wkb, Wvb, Qb, Kb, Vtp);

    flash_attn<<<dim3(256), dim3(512), 0, stream>>>(Qb, Kb, Vtp, bias, part, ml);
    combine_halves<<<dim3(BQ * SEQ), dim3(128), 0, stream>>>(part, ml, out);
}